// Round 12
// baseline (4564.245 us; speedup 1.0000x reference)
//
#include <hip/hip_runtime.h>

#define MDIM 4096
#define KDIM 4096
#define NDIM 11008
#define NGROUPS 32

#define BM 256
#define BN 256
#define BK 32
#define NT (KDIM / BK)   // 128 K-tiles
#define KB (KDIM * 2)    // row stride in bytes (8192)

typedef _Float16 f16x8 __attribute__((ext_vector_type(8)));
typedef float f32x4 __attribute__((ext_vector_type(4)));

typedef const unsigned int __attribute__((address_space(1))) *gas_t;
typedef unsigned int __attribute__((address_space(3))) *las_t;

__device__ __forceinline__ void gld_lds16(const void *g, void *l) {
  __builtin_amdgcn_global_load_lds((gas_t)g, (las_t)l, 16, 0, 0);
}

// Raw barrier with memory clobber (no implicit vm/lgkm drain).
#define BAR() asm volatile("s_barrier" ::: "memory")
#define VMW4() asm volatile("s_waitcnt vmcnt(4)" ::: "memory")
#define VMW2() asm volatile("s_waitcnt vmcnt(2)" ::: "memory")
#define VMW0() asm volatile("s_waitcnt vmcnt(0)" ::: "memory")
#define FENCE() __builtin_amdgcn_sched_barrier(0)

// ---------------- prepass: A fp32 -> f16 (split kernels measured faster
// than fused: R7 ~52us vs R8 ~63us; prepass is at its memory roofline) ------
__global__ __launch_bounds__(256) void cvt_a_kernel(const float *__restrict__ a,
                                                    _Float16 *__restrict__ o) {
  const int n8 = (MDIM * KDIM) / 8;
  for (int i = blockIdx.x * blockDim.x + threadIdx.x; i < n8;
       i += gridDim.x * blockDim.x) {
    const float4 v0 = *(const float4 *)(a + (size_t)i * 8);
    const float4 v1 = *(const float4 *)(a + (size_t)i * 8 + 4);
    f16x8 h;
    h[0] = (_Float16)v0.x; h[1] = (_Float16)v0.y;
    h[2] = (_Float16)v0.z; h[3] = (_Float16)v0.w;
    h[4] = (_Float16)v1.x; h[5] = (_Float16)v1.y;
    h[6] = (_Float16)v1.z; h[7] = (_Float16)v1.w;
    *(f16x8 *)(o + (size_t)i * 8) = h;
  }
}

// ---------------- prepass: W int32 -> f16 * scale ----------------
__global__ __launch_bounds__(256) void cvt_w_kernel(const int *__restrict__ w,
                                                    const float *__restrict__ s,
                                                    _Float16 *__restrict__ o) {
  const int n8 = (NDIM * KDIM) / 8;
  for (int i = blockIdx.x * blockDim.x + threadIdx.x; i < n8;
       i += gridDim.x * blockDim.x) {
    const size_t base = (size_t)i * 8;
    const int row = (int)(base >> 12);             // /KDIM
    const int g = ((int)(base & (KDIM - 1))) >> 7; // /GROUPSIZE
    const float sc = s[row * NGROUPS + g];
    const int4 w0 = *(const int4 *)(w + base);
    const int4 w1 = *(const int4 *)(w + base + 4);
    f16x8 h;
    h[0] = (_Float16)((float)w0.x * sc); h[1] = (_Float16)((float)w0.y * sc);
    h[2] = (_Float16)((float)w0.z * sc); h[3] = (_Float16)((float)w0.w * sc);
    h[4] = (_Float16)((float)w1.x * sc); h[5] = (_Float16)((float)w1.y * sc);
    h[6] = (_Float16)((float)w1.z * sc); h[7] = (_Float16)((float)w1.w * sc);
    *(f16x8 *)(o + base) = h;
  }
}

// ---------------- main GEMM: 256x256 tile, BK=32, 8 waves, 2 blocks/CU -----
// R9 champion schedule with BK halved (64->32): LDS = A dbuf 2x16KB + B
// tribuf 3x16KB = 80KB -> TWO blocks per CU (2x80KB = the full 160KiB),
// while the OUTPUT tile stays 256x256 (grid 688, panel reuse and FETCH at
// R9 levels - removes R10's cache-economy confound). Per-CU traffic per
// unit K identical to R9. Second resident block covers barrier/lgkm stalls.
// Per tile (halved R9): af0 = A mi0-3, af1 = A mi4-7 (1 b128 each, K=32 is
// one 16x16x32 k-step); B0r = cols QN0 (nj0-1), B1r = QN1. 32 MFMA/wave.
//   top: stage B(t+2)->bS (2 glds)
//   P1: read B1r<-B(t) QN1 (2) | 8 MFMA Q00 (af0 x B0r)
//   P2: read af1<-A(t) mi4-7 (4) | 8 MFMA Q01 (af0 x B1r)
//   mid: vmcnt(2) [in-flight oldest-first B(t+1)2, A(t+1)2, B(t+2)2 ->
//        retires B(t+1),A(t+1), keeps B(t+2)]; BAR
//   P3: read af0<-A(t+1) mi0-3 (4, An) | 8 MFMA Q11 (af1 x B1r)
//   P4: read B1r<-B(t+1) QN0 (2, Bn); stage A(t+2)->aC | 8 MFMA Q10
// Ledger (same proofs as R9, re-verified t=0/steady/NT-2/NT-1): bS holds
// B(t-1) whose last reads retire before t-1's mid-BAR; aC holds A(t) whose
// last reads (t's P2 + t-1's P3-prefetch) retire before t's mid-BAR; P4
// staging is post-BAR. A(t+1) is ~1 tile old at vmcnt(2) - never blocks.
// LDS rows are 64B (32 f16); XOR swizzle on the 4 16B slots:
// phys_slot = kslot ^ (row&3), applied to the pre-swizzled staging source
// AND the ds_read address (same uniform-bank structure as R9's 8-slot XOR).
__global__ __launch_bounds__(512, 4) void gemm_8phase(
    const _Float16 *__restrict__ Ah, const _Float16 *__restrict__ Wh,
    float *__restrict__ C) {
  // [0,32KB): A slots 0,1 (16KB each); [32KB,80KB): B slots 0,1,2 (16KB).
  __shared__ __align__(16) char Sh[81920];

  const int tid = threadIdx.x;
  const int l = tid & 63;
  const int w = tid >> 6;   // wave 0..7
  const int wm = w >> 2;    // 0..1 (M half: 128 rows)
  const int wn = w & 3;     // 0..3 (N quarter: 64 cols)

  // XCD-aware bijective swizzle: 688 blocks, 86 per XCD.
  const int wg = blockIdx.x;
  const int swz = (wg & 7) * 86 + (wg >> 3);
  const int bx = swz / 16;   // N tile 0..42
  const int by = swz % 16;   // M tile 0..15

  // staging source (pre-swizzled per lane): 4 lanes per row, 16 rows per
  // gld; lane l covers row w*32 + (l>>2) (+16 for the 2nd gld), 16B slot
  // (l&3) ^ ((l>>2)&3).
  const int sgk = (((l & 3) ^ ((l >> 2) & 3)) << 4);
  const char *Ag =
      (const char *)Ah + (size_t)(by * BM + w * 32 + (l >> 2)) * KB + sgk;
  const char *Bg =
      (const char *)Wh + (size_t)(bx * BN + w * 32 + (l >> 2)) * KB + sgk;

  // fragment-read offsets (bytes); 64B rows, slot XOR: kslot(l>>4) ^ (l&3)
  const int laneRow = (l & 15) * 64;
  const int kx = (((l >> 4) ^ (l & 3)) << 4);

  f32x4 acc[8][4] = {};
  f16x8 af0[4], af1[4], bfA[2], bfB[2];

  // rotating LDS slot offsets (bytes into Sh)
  unsigned aC = 0, aN = 16384;
  unsigned bC = 32768, bN = 49152, bS = 65536;

  // stage unit: 2 glds = 16KB tile (8 waves x 2KB; rows w*32..w*32+31)
#define STAGE_A(KT, OFF)                                                      \
  {                                                                           \
    const char *ap_ = Ag + (size_t)(KT) * 64;                                 \
    gld_lds16(ap_, (void *)(Sh + (OFF) + w * 2048));                          \
    gld_lds16(ap_ + (size_t)16 * KB,                                          \
              (void *)(Sh + (OFF) + w * 2048 + 1024));                        \
  }

#define STAGE_B(KT, OFF)                                                      \
  {                                                                           \
    const char *bp_ = Bg + (size_t)(KT) * 64;                                 \
    gld_lds16(bp_, (void *)(Sh + (OFF) + w * 2048));                          \
    gld_lds16(bp_ + (size_t)16 * KB,                                          \
              (void *)(Sh + (OFF) + w * 2048 + 1024));                        \
  }

  // single b128 fragment reads. ML = local reg index, MG = global mi.
#define RDA(DST, ML, MG, BASE)                                                \
  DST[ML] = *(const f16x8 *)((BASE) + wm * 8192 + (MG) * 1024 + laneRow + kx);

#define RDB(DST, NJ, QN, BASE)                                                \
  DST[NJ] = *(const f16x8 *)((BASE) + wn * 4096 + (QN) * 2048 +               \
                             (NJ) * 1024 + laneRow + kx);

  // 4-MFMA cluster: quadrant (QM,QN), local M-frags MI0..MI0+1, both nj
#define MMA4(AF, BF, QM, QN, MI0)                                             \
  __builtin_amdgcn_s_setprio(1);                                              \
  _Pragma("unroll") for (int mi = (MI0); mi < (MI0) + 2; ++mi)                \
      _Pragma("unroll") for (int nj = 0; nj < 2; ++nj)                        \
          acc[(QM) * 4 + mi][(QN) * 2 + nj] =                                 \
              __builtin_amdgcn_mfma_f32_16x16x32_f16(                         \
                  AF[mi], BF[nj], acc[(QM) * 4 + mi][(QN) * 2 + nj],          \
                  0, 0, 0);                                                   \
  __builtin_amdgcn_s_setprio(0);

  // TILE(T, B0r, B1r): B0r holds this tile's B-QN0 (loaded prev tile's P4);
  // B1r gets B-QN1-cur in P1, then next tile's B-QN0 in P4 (dead after Q11).
#define TILE(T, B0r, B1r)                                                     \
  {                                                                           \
    const bool s1 = (T) + 1 < NT;                                             \
    const bool s2 = (T) + 2 < NT;                                             \
    const char *Ac = (const char *)Sh + aC;                                   \
    const char *An = (const char *)Sh + aN;                                   \
    const char *Bc = (const char *)Sh + bC;                                   \
    const char *Bn = (const char *)Sh + bN;                                   \
    /* top: stage B(T+2) -> bS (holds B(T-1); reads ended pre prev BAR) */    \
    if (s2) { STAGE_B((T) + 2, bS); }                                         \
    /* P1: Q00 on (af0,B0r); interleave B-QN1-cur reads into B1r */           \
    RDB(B1r, 0, 1, Bc);                                                       \
    FENCE(); MMA4(af0, B0r, 0, 0, 0);                                         \
    RDB(B1r, 1, 1, Bc);                                                       \
    FENCE(); MMA4(af0, B0r, 0, 0, 2);                                         \
    /* P2: Q01 on (af0,B1r); interleave A mi4-7 reads into af1 */             \
    RDA(af1, 0, 4, Ac); RDA(af1, 1, 5, Ac);                                   \
    FENCE(); MMA4(af0, B1r, 0, 1, 0);                                         \
    RDA(af1, 2, 6, Ac); RDA(af1, 3, 7, Ac);                                   \
    FENCE(); MMA4(af0, B1r, 0, 1, 2);                                         \
    /* mid: counted retire + publish. In-flight oldest-first:                 \
       [B(T+1)2, A(T+1)2, B(T+2)2] -> vmcnt(2) retires B(T+1),A(T+1). */     \
    if (s2) { VMW2(); } else { VMW0(); }                                      \
    BAR();                                                                    \
    /* P3: Q11 on (af1,B1r); interleave af0-next reads (An published) */      \
    if (s1) { RDA(af0, 0, 0, An); RDA(af0, 1, 1, An); }                       \
    FENCE(); MMA4(af1, B1r, 1, 1, 0);                                         \
    if (s1) { RDA(af0, 2, 2, An); RDA(af0, 3, 3, An); }                       \
    FENCE(); MMA4(af1, B1r, 1, 1, 2);                                         \
    /* P4: Q10 on (af1,B0r); B-QN0-next reads + stage A(T+2)->aC */           \
    if (s1) { RDB(B1r, 0, 0, Bn); }                                           \
    FENCE(); MMA4(af1, B0r, 1, 0, 0);                                         \
    if (s1) { RDB(B1r, 1, 0, Bn); }                                           \
    if (s2) { STAGE_A((T) + 2, aC); }                                         \
    FENCE(); MMA4(af1, B0r, 1, 0, 2);                                         \
    /* rotate LDS slots */                                                    \
    { const unsigned ta = aC; aC = aN; aN = ta; }                             \
    { const unsigned tb = bC; bC = bN; bN = bS; bS = tb; }                    \
  }

  // prologue. vmcnt order: A0,B0 (oldest 4, retired by VMW4), B1, A1 ->
  // in-flight [B(1)2, A(1)2] entering t=0.
  STAGE_A(0, aC);
  STAGE_B(0, bC);
  STAGE_B(1, bN);
  STAGE_A(1, aN);
  VMW4();
  BAR();
  {
    const char *A0 = (const char *)Sh + aC;
    const char *B0p = (const char *)Sh + bC;
    RDA(af0, 0, 0, A0); RDA(af0, 1, 1, A0);
    RDA(af0, 2, 2, A0); RDA(af0, 3, 3, A0);
    RDB(bfA, 0, 0, B0p); RDB(bfA, 1, 0, B0p);
  }

  for (int t = 0; t < NT; t += 2) {
    TILE(t, bfA, bfB);
    TILE(t + 1, bfB, bfA);
  }

#undef TILE
#undef STAGE_A
#undef STAGE_B
#undef RDA
#undef RDB
#undef MMA4

  // C/D layout: col = lane&15, row = (lane>>4)*4 + reg
  const int fr = l & 15, fq = l >> 4;
  float *Cb = C + (size_t)(by * BM + wm * 128) * NDIM + bx * BN + wn * 64;
#pragma unroll
  for (int i = 0; i < 8; ++i)
#pragma unroll
    for (int j = 0; j < 4; ++j)
#pragma unroll
      for (int r = 0; r < 4; ++r)
        Cb[(size_t)(i * 16 + fq * 4 + r) * NDIM + j * 16 + fr] = acc[i][j][r];
}

// ---------------- fallback: fused dequant GEMM (no workspace needed) -------
__global__ __launch_bounds__(256) void gemm_fused(const float *__restrict__ A,
                                                  const int *__restrict__ W,
                                                  const float *__restrict__ S,
                                                  float *__restrict__ C) {
  __shared__ _Float16 Asf[128 * 64];
  __shared__ _Float16 Bsf[128 * 64];
  const int tid = threadIdx.x;
  const int lane = tid & 63;
  const int wv = tid >> 6;
  const int wm = wv >> 1, wn = wv & 1;
  const int bx = blockIdx.x, by = blockIdx.y;
  const int srow = tid >> 1;
  const int skof = (tid & 1) * 32;

  const float *Ab = A + (size_t)(by * 128 + srow) * KDIM + skof;
  const int *Wb = W + (size_t)(bx * 128 + srow) * KDIM + skof;
  const float *Sb = S + (size_t)(bx * 128 + srow) * NGROUPS;

  f32x4 acc[4][4] = {};
  float4 ar[8];
  int4 wr[8];
  float sc;

#pragma unroll
  for (int u = 0; u < 8; ++u) {
    ar[u] = *(const float4 *)(Ab + u * 4);
    wr[u] = *(const int4 *)(Wb + u * 4);
  }
  sc = Sb[0];

  const int fr = lane & 15;
  const int fq = lane >> 4;
  const int kbase = fq * 8;

  for (int kt = 0; kt < KDIM / 64; ++kt) {
    __syncthreads();
    _Float16 *Ad = &Asf[srow * 64 + skof];
    _Float16 *Bd = &Bsf[srow * 64 + skof];
#pragma unroll
    for (int u = 0; u < 4; ++u) {
      const float4 a0 = ar[2 * u], a1 = ar[2 * u + 1];
      const int4 b0 = wr[2 * u], b1 = wr[2 * u + 1];
      f16x8 ha, hb;
      ha[0] = (_Float16)a0.x; ha[1] = (_Float16)a0.y;
      ha[2] = (_Float16)a0.z; ha[3] = (_Float16)a0.w;
      ha[4] = (_Float16)a1.x; ha[5] = (_Float16)a1.y;
      ha[6] = (_Float16)a1.z; ha[7] = (_Float16)a1.w;
      hb[0] = (_Float16)((float)b0.x * sc); hb[1] = (_Float16)((float)b0.y * sc);
      hb[2] = (_Float16)((float)b0.z * sc); hb[3] = (_Float16)((float)b0.w * sc);
      hb[4] = (_Float16)((float)b1.x * sc); hb[5] = (_Float16)((float)b1.y * sc);
      hb[6] = (_Float16)((float)b1.z * sc); hb[7] = (_Float16)((float)b1.w * sc);
      *(f16x8 *)(Ad + u * 8) = ha;
      *(f16x8 *)(Bd + u * 8) = hb;
    }
    if (kt + 1 < KDIM / 64) {
      const float *An = Ab + (kt + 1) * 64;
      const int *Wn = Wb + (kt + 1) * 64;
#pragma unroll
      for (int u = 0; u < 8; ++u) {
        ar[u] = *(const float4 *)(An + u * 4);
        wr[u] = *(const int4 *)(Wn + u * 4);
      }
      sc = Sb[(kt + 1) >> 1];
    }
    __syncthreads();
#pragma unroll
    for (int ks = 0; ks < 2; ++ks) {
      f16x8 afv[4], bfv[4];
      const int kof = ks * 32 + kbase;
#pragma unroll
      for (int i = 0; i < 4; ++i) {
        afv[i] = *(const f16x8 *)&Asf[(wm * 64 + i * 16 + fr) * 64 + kof];
        bfv[i] = *(const f16x8 *)&Bsf[(wn * 64 + i * 16 + fr) * 64 + kof];
      }
#pragma unroll
      for (int i = 0; i < 4; ++i)
#pragma unroll
        for (int j = 0; j < 4; ++j)
          acc[i][j] = __builtin_amdgcn_mfma_f32_16x16x32_f16(afv[i], bfv[j],
                                                             acc[i][j], 0, 0, 0);
    }
  }

  float *Cb = C + (size_t)(by * 128 + wm * 64) * NDIM + bx * 128 + wn * 64;
#pragma unroll
  for (int i = 0; i < 4; ++i)
#pragma unroll
    for (int j = 0; j < 4; ++j)
#pragma unroll
      for (int r = 0; r < 4; ++r)
        Cb[(size_t)(i * 16 + fq * 4 + r) * NDIM + j * 16 + fr] = acc[i][j][r];
}

extern "C" void kernel_launch(void *const *d_in, const int *in_sizes, int n_in,
                              void *d_out, int out_size, void *d_ws,
                              size_t ws_size, hipStream_t stream) {
  (void)in_sizes; (void)n_in; (void)out_size;
  const float *A = (const float *)d_in[0];
  const int *W = (const int *)d_in[1];
  const float *S = (const float *)d_in[2];
  float *C = (float *)d_out;

  const size_t needA = (size_t)MDIM * KDIM * sizeof(_Float16);
  const size_t needW = (size_t)NDIM * KDIM * sizeof(_Float16);

  if (ws_size >= needA + needW) {
    _Float16 *Ahp = (_Float16 *)d_ws;
    _Float16 *Whp = (_Float16 *)((char *)d_ws + needA);
    cvt_a_kernel<<<2048, 256, 0, stream>>>(A, Ahp);
    cvt_w_kernel<<<2048, 256, 0, stream>>>(W, S, Whp);
    gemm_8phase<<<(MDIM / BM) * (NDIM / BN), 512, 0, stream>>>(Ahp, Whp, C);
  } else {
    dim3 grid(NDIM / 128, MDIM / 128);
    gemm_fused<<<grid, 256, 0, stream>>>(A, W, S, C);
  }
}

// Round 13
// 398.132 us; speedup vs baseline: 11.4641x; 11.4641x over previous
//
#include <hip/hip_runtime.h>

#define MDIM 4096
#define KDIM 4096
#define NDIM 11008
#define NGROUPS 32

#define BM 256
#define BN 256
#define BK 64
#define NT (KDIM / BK)   // 64 K-tiles
#define KB (KDIM * 2)    // row stride in bytes (8192)

typedef _Float16 f16x8 __attribute__((ext_vector_type(8)));
typedef float f32x4 __attribute__((ext_vector_type(4)));

typedef const unsigned int __attribute__((address_space(1))) *gas_t;
typedef unsigned int __attribute__((address_space(3))) *las_t;

__device__ __forceinline__ void gld_lds16(const void *g, void *l) {
  __builtin_amdgcn_global_load_lds((gas_t)g, (las_t)l, 16, 0, 0);
}

// Raw barrier with memory clobber (no implicit vm/lgkm drain).
#define BAR() asm volatile("s_barrier" ::: "memory")
#define VMW8() asm volatile("s_waitcnt vmcnt(8)" ::: "memory")
#define VMW4() asm volatile("s_waitcnt vmcnt(4)" ::: "memory")
#define VMW0() asm volatile("s_waitcnt vmcnt(0)" ::: "memory")
#define FENCE() __builtin_amdgcn_sched_barrier(0)

// ---------------- prepass: A fp32 -> f16 (split kernels measured faster
// than fused: R7 ~52us vs R8 ~63us; prepass is at its memory roofline) ------
__global__ __launch_bounds__(256) void cvt_a_kernel(const float *__restrict__ a,
                                                    _Float16 *__restrict__ o) {
  const int n8 = (MDIM * KDIM) / 8;
  for (int i = blockIdx.x * blockDim.x + threadIdx.x; i < n8;
       i += gridDim.x * blockDim.x) {
    const float4 v0 = *(const float4 *)(a + (size_t)i * 8);
    const float4 v1 = *(const float4 *)(a + (size_t)i * 8 + 4);
    f16x8 h;
    h[0] = (_Float16)v0.x; h[1] = (_Float16)v0.y;
    h[2] = (_Float16)v0.z; h[3] = (_Float16)v0.w;
    h[4] = (_Float16)v1.x; h[5] = (_Float16)v1.y;
    h[6] = (_Float16)v1.z; h[7] = (_Float16)v1.w;
    *(f16x8 *)(o + (size_t)i * 8) = h;
  }
}

// ---------------- prepass: W int32 -> f16 * scale ----------------
__global__ __launch_bounds__(256) void cvt_w_kernel(const int *__restrict__ w,
                                                    const float *__restrict__ s,
                                                    _Float16 *__restrict__ o) {
  const int n8 = (NDIM * KDIM) / 8;
  for (int i = blockIdx.x * blockDim.x + threadIdx.x; i < n8;
       i += gridDim.x * blockDim.x) {
    const size_t base = (size_t)i * 8;
    const int row = (int)(base >> 12);             // /KDIM
    const int g = ((int)(base & (KDIM - 1))) >> 7; // /GROUPSIZE
    const float sc = s[row * NGROUPS + g];
    const int4 w0 = *(const int4 *)(w + base);
    const int4 w1 = *(const int4 *)(w + base + 4);
    f16x8 h;
    h[0] = (_Float16)((float)w0.x * sc); h[1] = (_Float16)((float)w0.y * sc);
    h[2] = (_Float16)((float)w0.z * sc); h[3] = (_Float16)((float)w0.w * sc);
    h[4] = (_Float16)((float)w1.x * sc); h[5] = (_Float16)((float)w1.y * sc);
    h[6] = (_Float16)((float)w1.z * sc); h[7] = (_Float16)((float)w1.w * sc);
    *(f16x8 *)(o + base) = h;
  }
}

// ---------------- main GEMM: 256x256 tile, BK=64, 8 waves ------------------
// R9 CHAMPION (measured 400.1us total; GEMM 342-348us, MfmaUtil ~49).
// Triple-buffered B, single barrier per tile, balanced 4/8/8/4 read phases,
// fine MMA4/read interleave.
// Ledger (A dbuf 64KB + B tribuf 96KB = 160KB):
//  * B(t+2) staged at tile top into bS (holds B(t-1); reads ended before
//    tile-(t-1)'s BAR).
//  * A(t+2) staged at tile-t P4 (post-BAR) into aC (holds A(t); last reads
//    P2, pre-BAR). A(t+1) thus ~2900cyc old at this tile's vmcnt(4).
//  * vmcnt(4) before BAR: in-flight oldest-first [B(t+1)4, A(t+1)4, B(t+2)4]
//    -> retires B(t+1),A(t+1); keeps B(t+2) in flight.
//  * P3 reads af0-next from An=A(t+1), P4 reads B0-next from Bn=B(t+1):
//    both covered by every wave's pre-BAR vmcnt(4) + the BAR.
// Register parity: B0 spans the tile; B1 dead after Q11 receives next tile's
// B-QN0 during Q10. af0 dead after Q01, reloaded in P3; af1 reloaded each P2.
// LDS XOR-swizzle (16B involution): phys_koff = koff ^ ((row&7)*16), applied
// to the pre-swizzled staging source AND the ds_read address.
// Session ceiling notes: occupancy locked at 2 waves/SIMD (acc 128 + frags
// ~80 VGPR > 128-reg cap for 4 waves/SIMD - R12 spill = 14x); 128^2 tile
// breaks cache economy (R10 FETCH 2.5x); 32x32 shape closed (R3 conflicts,
// R11 staging scatter); schedule converged (R0-R8 bracket).
__global__ __launch_bounds__(512, 2) void gemm_8phase(
    const _Float16 *__restrict__ Ah, const _Float16 *__restrict__ Wh,
    float *__restrict__ C) {
  // [0,64KB): A slots 0,1 (32KB each); [64KB,160KB): B slots 0,1,2.
  __shared__ __align__(16) char Sh[163840];

  const int tid = threadIdx.x;
  const int l = tid & 63;
  const int w = tid >> 6;   // wave 0..7
  const int wm = w >> 2;    // 0..1 (M half)
  const int wn = w & 3;     // 0..3 (N quarter)

  // XCD-aware bijective swizzle: 688 blocks, 86 per XCD.
  const int wg = blockIdx.x;
  const int swz = (wg & 7) * 86 + (wg >> 3);
  const int bx = swz / 16;   // N tile 0..42
  const int by = swz % 16;   // M tile 0..15

  // staging source (pre-swizzled per lane)
  const int srow = l >> 3;
  const int gk = ((l & 7) ^ srow) * 16;
  const char *Ag =
      (const char *)Ah + (size_t)(by * BM + w * 8 + srow) * KB + gk;
  const char *Bg =
      (const char *)Wh + (size_t)(bx * BN + w * 8 + srow) * KB + gk;

  // fragment-read offsets (bytes)
  const int laneRow = (l & 15) * (BK * 2);
  const int kx0 = ((l >> 4) * 16) ^ ((l & 7) * 16);
  const int kx1 = kx0 ^ 64;

  f32x4 acc[8][4] = {};
  f16x8 af0[4][2], af1[4][2], bfA[2][2], bfB[2][2];

  // rotating LDS slot offsets (bytes into Sh)
  unsigned aC = 0, aN = 32768;
  unsigned bC = 65536, bN = 98304, bS = 131072;

#define STAGE2_A(KT, OFF, S0)                                                 \
  {                                                                           \
    const char *ap_ = Ag + (size_t)(KT) * (BK * 2);                           \
    gld_lds16(ap_ + (size_t)(S0) * (64 * KB),                                 \
              (void *)(Sh + (OFF) + (S0) * 8192 + w * 1024));                 \
    gld_lds16(ap_ + (size_t)((S0) + 1) * (64 * KB),                           \
              (void *)(Sh + (OFF) + ((S0) + 1) * 8192 + w * 1024));           \
  }

#define STAGE2_B(KT, OFF, S0)                                                 \
  {                                                                           \
    const char *bp_ = Bg + (size_t)(KT) * (BK * 2);                           \
    gld_lds16(bp_ + (size_t)(S0) * (64 * KB),                                 \
              (void *)(Sh + (OFF) + (S0) * 8192 + w * 1024));                 \
    gld_lds16(bp_ + (size_t)((S0) + 1) * (64 * KB),                           \
              (void *)(Sh + (OFF) + ((S0) + 1) * 8192 + w * 1024));           \
  }

  // 2-read fragment loads (one mi / one nj, both k-halves)
#define RDA2(DST, MI, QM, BASE)                                               \
  {                                                                           \
    const char *ba_ = (BASE) + (wm * 128 + (QM) * 64) * (BK * 2) + laneRow;   \
    DST[MI][0] = *(const f16x8 *)(ba_ + (MI) * 2048 + kx0);                   \
    DST[MI][1] = *(const f16x8 *)(ba_ + (MI) * 2048 + kx1);                   \
  }

#define RDB2(DST, NJ, QN, BASE)                                               \
  {                                                                           \
    const char *bb_ = (BASE) + (wn * 64 + (QN) * 32) * (BK * 2) + laneRow;    \
    DST[NJ][0] = *(const f16x8 *)(bb_ + (NJ) * 2048 + kx0);                   \
    DST[NJ][1] = *(const f16x8 *)(bb_ + (NJ) * 2048 + kx1);                   \
  }

  // 4-MFMA cluster: quadrant (QM,QN), k-step KS, M-frags MI0..MI0+1
#define MMA4(AF, BF, QM, QN, KS, MI0)                                         \
  __builtin_amdgcn_s_setprio(1);                                              \
  _Pragma("unroll") for (int mi = (MI0); mi < (MI0) + 2; ++mi)                \
      _Pragma("unroll") for (int nj = 0; nj < 2; ++nj)                        \
          acc[(QM) * 4 + mi][(QN) * 2 + nj] =                                 \
              __builtin_amdgcn_mfma_f32_16x16x32_f16(                         \
                  AF[mi][KS], BF[nj][KS],                                     \
                  acc[(QM) * 4 + mi][(QN) * 2 + nj], 0, 0, 0);                \
  __builtin_amdgcn_s_setprio(0);

  // TILE(T, B0, B1): B0 holds this tile's B-QN0 (loaded at previous tile's
  // P4); B1 gets B-QN1-cur in P1, then next tile's B-QN0 in P4.
#define TILE(T, B0, B1)                                                       \
  {                                                                           \
    const bool s1 = (T) + 1 < NT;                                             \
    const bool s2 = (T) + 2 < NT;                                             \
    const char *Ac = (const char *)Sh + aC;                                   \
    const char *An = (const char *)Sh + aN;                                   \
    const char *Bc = (const char *)Sh + bC;                                   \
    const char *Bn = (const char *)Sh + bN;                                   \
    /* top: stage B(T+2) -> bS (holds B(T-1); reads ended pre prev BAR) */    \
    if (s2) { STAGE2_B((T) + 2, bS, 0); STAGE2_B((T) + 2, bS, 2); }           \
    /* P1: Q00 on (af0,B0); interleave B-QN1-cur reads into B1 */             \
    RDB2(B1, 0, 1, Bc);                                                       \
    FENCE(); MMA4(af0, B0, 0, 0, 0, 0);                                       \
    RDB2(B1, 1, 1, Bc);                                                       \
    FENCE(); MMA4(af0, B0, 0, 0, 0, 2);                                       \
    FENCE(); MMA4(af0, B0, 0, 0, 1, 0);                                       \
    FENCE(); MMA4(af0, B0, 0, 0, 1, 2);                                       \
    /* P2: Q01 on (af0,B1); interleave A-QM1-cur reads into af1 */            \
    RDA2(af1, 0, 1, Ac);                                                      \
    FENCE(); MMA4(af0, B1, 0, 1, 0, 0);                                       \
    RDA2(af1, 1, 1, Ac);                                                      \
    FENCE(); MMA4(af0, B1, 0, 1, 0, 2);                                       \
    RDA2(af1, 2, 1, Ac);                                                      \
    FENCE(); MMA4(af0, B1, 0, 1, 1, 0);                                       \
    RDA2(af1, 3, 1, Ac);                                                      \
    FENCE(); MMA4(af0, B1, 0, 1, 1, 2);                                       \
    /* mid: counted retire + publish. In-flight oldest-first:                 \
       [B(T+1)4, A(T+1)4, B(T+2)4] -> vmcnt(4) retires B(T+1),A(T+1). */     \
    if (s2) { VMW4(); } else { VMW0(); }                                      \
    BAR();                                                                    \
    /* P3: Q11 on (af1,B1); interleave af0-next reads (An published) */       \
    if (s1) { RDA2(af0, 0, 0, An); RDA2(af0, 1, 0, An); }                     \
    FENCE(); MMA4(af1, B1, 1, 1, 0, 0);                                       \
    if (s1) { RDA2(af0, 2, 0, An); }                                          \
    FENCE(); MMA4(af1, B1, 1, 1, 0, 2);                                       \
    if (s1) { RDA2(af0, 3, 0, An); }                                          \
    FENCE(); MMA4(af1, B1, 1, 1, 1, 0);                                       \
    FENCE(); MMA4(af1, B1, 1, 1, 1, 2);                                       \
    /* P4: Q10 on (af1,B0); interleave B0-next reads + stage A(T+2)->aC */    \
    if (s1) { RDB2(B1, 0, 0, Bn); }                                           \
    FENCE(); MMA4(af1, B0, 1, 0, 0, 0);                                       \
    if (s1) { RDB2(B1, 1, 0, Bn); }                                           \
    FENCE(); MMA4(af1, B0, 1, 0, 0, 2);                                       \
    if (s2) { STAGE2_A((T) + 2, aC, 0); }                                     \
    FENCE(); MMA4(af1, B0, 1, 0, 1, 0);                                       \
    if (s2) { STAGE2_A((T) + 2, aC, 2); }                                     \
    FENCE(); MMA4(af1, B0, 1, 0, 1, 2);                                       \
    /* rotate LDS slots */                                                    \
    { const unsigned ta = aC; aC = aN; aN = ta; }                             \
    { const unsigned tb = bC; bC = bN; bN = bS; bS = tb; }                    \
  }

  // prologue. Issue order matters for vmcnt: A(0),B(0) (oldest 8, retired by
  // VMW8), then B(1), then A(1) -> in-flight [B(1)4, A(1)4] entering t=0.
  STAGE2_A(0, aC, 0); STAGE2_A(0, aC, 2);
  STAGE2_B(0, bC, 0); STAGE2_B(0, bC, 2);
  STAGE2_B(1, bN, 0); STAGE2_B(1, bN, 2);
  STAGE2_A(1, aN, 0); STAGE2_A(1, aN, 2);
  VMW8();
  BAR();
  {
    const char *A0 = (const char *)Sh + aC;
    const char *B0p = (const char *)Sh + bC;
    RDA2(af0, 0, 0, A0); RDA2(af0, 1, 0, A0);
    RDA2(af0, 2, 0, A0); RDA2(af0, 3, 0, A0);
    RDB2(bfA, 0, 0, B0p); RDB2(bfA, 1, 0, B0p);
  }

  for (int t = 0; t < NT; t += 2) {
    TILE(t, bfA, bfB);
    TILE(t + 1, bfB, bfA);
  }

#undef TILE
#undef STAGE2_A
#undef STAGE2_B
#undef RDA2
#undef RDB2
#undef MMA4

  // C/D layout: col = lane&15, row = (lane>>4)*4 + reg
  const int fr = l & 15, fq = l >> 4;
  float *Cb = C + (size_t)(by * BM + wm * 128) * NDIM + bx * BN + wn * 64;
#pragma unroll
  for (int i = 0; i < 8; ++i)
#pragma unroll
    for (int j = 0; j < 4; ++j)
#pragma unroll
      for (int r = 0; r < 4; ++r)
        Cb[(size_t)(i * 16 + fq * 4 + r) * NDIM + j * 16 + fr] = acc[i][j][r];
}

// ---------------- fallback: fused dequant GEMM (no workspace needed) -------
__global__ __launch_bounds__(256) void gemm_fused(const float *__restrict__ A,
                                                  const int *__restrict__ W,
                                                  const float *__restrict__ S,
                                                  float *__restrict__ C) {
  __shared__ _Float16 Asf[128 * 64];
  __shared__ _Float16 Bsf[128 * 64];
  const int tid = threadIdx.x;
  const int lane = tid & 63;
  const int wv = tid >> 6;
  const int wm = wv >> 1, wn = wv & 1;
  const int bx = blockIdx.x, by = blockIdx.y;
  const int srow = tid >> 1;
  const int skof = (tid & 1) * 32;

  const float *Ab = A + (size_t)(by * 128 + srow) * KDIM + skof;
  const int *Wb = W + (size_t)(bx * 128 + srow) * KDIM + skof;
  const float *Sb = S + (size_t)(bx * 128 + srow) * NGROUPS;

  f32x4 acc[4][4] = {};
  float4 ar[8];
  int4 wr[8];
  float sc;

#pragma unroll
  for (int u = 0; u < 8; ++u) {
    ar[u] = *(const float4 *)(Ab + u * 4);
    wr[u] = *(const int4 *)(Wb + u * 4);
  }
  sc = Sb[0];

  const int fr = lane & 15;
  const int fq = lane >> 4;
  const int kbase = fq * 8;

  for (int kt = 0; kt < KDIM / 64; ++kt) {
    __syncthreads();
    _Float16 *Ad = &Asf[srow * 64 + skof];
    _Float16 *Bd = &Bsf[srow * 64 + skof];
#pragma unroll
    for (int u = 0; u < 4; ++u) {
      const float4 a0 = ar[2 * u], a1 = ar[2 * u + 1];
      const int4 b0 = wr[2 * u], b1 = wr[2 * u + 1];
      f16x8 ha, hb;
      ha[0] = (_Float16)a0.x; ha[1] = (_Float16)a0.y;
      ha[2] = (_Float16)a0.z; ha[3] = (_Float16)a0.w;
      ha[4] = (_Float16)a1.x; ha[5] = (_Float16)a1.y;
      ha[6] = (_Float16)a1.z; ha[7] = (_Float16)a1.w;
      hb[0] = (_Float16)((float)b0.x * sc); hb[1] = (_Float16)((float)b0.y * sc);
      hb[2] = (_Float16)((float)b0.z * sc); hb[3] = (_Float16)((float)b0.w * sc);
      hb[4] = (_Float16)((float)b1.x * sc); hb[5] = (_Float16)((float)b1.y * sc);
      hb[6] = (_Float16)((float)b1.z * sc); hb[7] = (_Float16)((float)b1.w * sc);
      *(f16x8 *)(Ad + u * 8) = ha;
      *(f16x8 *)(Bd + u * 8) = hb;
    }
    if (kt + 1 < KDIM / 64) {
      const float *An = Ab + (kt + 1) * 64;
      const int *Wn = Wb + (kt + 1) * 64;
#pragma unroll
      for (int u = 0; u < 8; ++u) {
        ar[u] = *(const float4 *)(An + u * 4);
        wr[u] = *(const int4 *)(Wn + u * 4);
      }
      sc = Sb[(kt + 1) >> 1];
    }
    __syncthreads();
#pragma unroll
    for (int ks = 0; ks < 2; ++ks) {
      f16x8 afv[4], bfv[4];
      const int kof = ks * 32 + kbase;
#pragma unroll
      for (int i = 0; i < 4; ++i) {
        afv[i] = *(const f16x8 *)&Asf[(wm * 64 + i * 16 + fr) * 64 + kof];
        bfv[i] = *(const f16x8 *)&Bsf[(wn * 64 + i * 16 + fr) * 64 + kof];
      }
#pragma unroll
      for (int i = 0; i < 4; ++i)
#pragma unroll
        for (int j = 0; j < 4; ++j)
          acc[i][j] = __builtin_amdgcn_mfma_f32_16x16x32_f16(afv[i], bfv[j],
                                                             acc[i][j], 0, 0, 0);
    }
  }

  float *Cb = C + (size_t)(by * 128 + wm * 64) * NDIM + bx * 128 + wn * 64;
#pragma unroll
  for (int i = 0; i < 4; ++i)
#pragma unroll
    for (int j = 0; j < 4; ++j)
#pragma unroll
      for (int r = 0; r < 4; ++r)
        Cb[(size_t)(i * 16 + fq * 4 + r) * NDIM + j * 16 + fr] = acc[i][j][r];
}

extern "C" void kernel_launch(void *const *d_in, const int *in_sizes, int n_in,
                              void *d_out, int out_size, void *d_ws,
                              size_t ws_size, hipStream_t stream) {
  (void)in_sizes; (void)n_in; (void)out_size;
  const float *A = (const float *)d_in[0];
  const int *W = (const int *)d_in[1];
  const float *S = (const float *)d_in[2];
  float *C = (float *)d_out;

  const size_t needA = (size_t)MDIM * KDIM * sizeof(_Float16);
  const size_t needW = (size_t)NDIM * KDIM * sizeof(_Float16);

  if (ws_size >= needA + needW) {
    _Float16 *Ahp = (_Float16 *)d_ws;
    _Float16 *Whp = (_Float16 *)((char *)d_ws + needA);
    cvt_a_kernel<<<2048, 256, 0, stream>>>(A, Ahp);
    cvt_w_kernel<<<2048, 256, 0, stream>>>(W, S, Whp);
    gemm_8phase<<<(MDIM / BM) * (NDIM / BN), 512, 0, stream>>>(Ahp, Whp, C);
  } else {
    dim3 grid(NDIM / 128, MDIM / 128);
    gemm_fused<<<grid, 256, 0, stream>>>(A, W, S, C);
  }
}